// Round 11
// baseline (567.285 us; speedup 1.0000x reference)
//
#include <hip/hip_runtime.h>
#include <math.h>

#define NF 128          // feature width (both in and out of every layer)
#define SCAN_CHUNK 1024
#define BUCK_SHIFT 9    // 512 nodes per bucket
#define BUCK_CAP 20480  // slots per bucket (avg 16384 for E=3.2M; +32 sigma)
#define NBUCK_MAX 256   // allocated buckets (used: ceil(N/512) = 196)
#define ECHUNK 2048     // edges per block-chunk in k_bucket

typedef int      vint4   __attribute__((ext_vector_type(4)));
typedef float    vfloat4 __attribute__((ext_vector_type(4)));
typedef float    f32x4   __attribute__((ext_vector_type(4)));
typedef _Float16 vhalf4  __attribute__((ext_vector_type(4)));
typedef _Float16 vhalf8  __attribute__((ext_vector_type(8)));

// ---------------------------------------------------------------------------
// Pass 1: bucketize edges by col range (512 nodes / bucket), ONE scan of the
// edge list. Entry = packed (c_local<<17 | r)  [valid for N <= 131072].
// ---------------------------------------------------------------------------
__global__ __launch_bounds__(256) void k_bucket(const int* __restrict__ row,
                                                const int* __restrict__ col,
                                                int* __restrict__ gcur,
                                                int* __restrict__ bdata, int E) {
  __shared__ int bcnt[NBUCK_MAX];
  __shared__ int bstage[NBUCK_MAX][32];
  const int tid = threadIdx.x;
  const int nChunks = (E + ECHUNK - 1) / ECHUNK;

  for (int chunk = blockIdx.x; chunk < nChunks; chunk += gridDim.x) {
    bcnt[tid] = 0;
    __syncthreads();

    const int cbase = chunk * ECHUNK;
    if (cbase + ECHUNK <= E) {
      const vint4* r4 = reinterpret_cast<const vint4*>(row) + (cbase >> 2) + 2 * tid;
      const vint4* c4 = reinterpret_cast<const vint4*>(col) + (cbase >> 2) + 2 * tid;
      vint4 ra = __builtin_nontemporal_load(&r4[0]);
      vint4 rb = __builtin_nontemporal_load(&r4[1]);
      vint4 ca = __builtin_nontemporal_load(&c4[0]);
      vint4 cb = __builtin_nontemporal_load(&c4[1]);
      int rr[8] = {ra.x, ra.y, ra.z, ra.w, rb.x, rb.y, rb.z, rb.w};
      int cc[8] = {ca.x, ca.y, ca.z, ca.w, cb.x, cb.y, cb.z, cb.w};
#pragma unroll
      for (int j = 0; j < 8; ++j) {
        int b = cc[j] >> BUCK_SHIFT;
        int packed = ((cc[j] & ((1 << BUCK_SHIFT) - 1)) << 17) | rr[j];
        int pos = atomicAdd(&bcnt[b], 1);
        if (pos < 32) {
          bstage[b][pos] = packed;
        } else {                                   // overflow (rare): direct append
          int p = atomicAdd(&gcur[b], 1);
          if (p < BUCK_CAP) bdata[b * BUCK_CAP + p] = packed;
        }
      }
    } else {
      for (int j = 0; j < 8; ++j) {
        int e = cbase + tid + j * 256;
        if (e < E) {
          int c = col[e], r = row[e];
          int b = c >> BUCK_SHIFT;
          int packed = ((c & ((1 << BUCK_SHIFT) - 1)) << 17) | r;
          int pos = atomicAdd(&bcnt[b], 1);
          if (pos < 32) {
            bstage[b][pos] = packed;
          } else {
            int p = atomicAdd(&gcur[b], 1);
            if (p < BUCK_CAP) bdata[b * BUCK_CAP + p] = packed;
          }
        }
      }
    }
    __syncthreads();

    int k = bcnt[tid];
    if (k > 32) k = 32;
    if (k > 0) {
      int p = atomicAdd(&gcur[tid], k);
      for (int i = 0; i < k && p + i < BUCK_CAP; ++i)
        bdata[tid * BUCK_CAP + p + i] = bstage[tid][i];
    }
    __syncthreads();
  }
}

// ---------------------------------------------------------------------------
// Pass 2a: per-bucket LDS histogram -> dense cnt write.
// ---------------------------------------------------------------------------
__global__ __launch_bounds__(256) void k_hist(const int* __restrict__ gcur,
                                              const int* __restrict__ bdata,
                                              int* __restrict__ cnt, int N) {
  __shared__ int hist[1 << BUCK_SHIFT];
  const int b = blockIdx.x;
  const int tid = threadIdx.x;
  hist[tid] = 0;
  hist[tid + 256] = 0;
  __syncthreads();
  int nb = gcur[b];
  if (nb > BUCK_CAP) nb = BUCK_CAP;
  const int* bd = bdata + (size_t)b * BUCK_CAP;
  for (int i = tid; i < nb; i += 256) atomicAdd(&hist[bd[i] >> 17], 1);
  __syncthreads();
  int base = b << BUCK_SHIFT;
#pragma unroll
  for (int k = 0; k < (1 << BUCK_SHIFT); k += 256) {
    int node = base + k + tid;
    if (node < N) cnt[node] = hist[k + tid];
  }
}

// ---------------------------------------------------------------------------
// Ordered exclusive prefix-sum of cnt -> offs. k_scanB needs nChunks <= 128.
// ---------------------------------------------------------------------------
__global__ __launch_bounds__(256) void k_scanA(const int* __restrict__ cnt,
                                               int* __restrict__ chunkTot, int N) {
  int c0 = blockIdx.x * SCAN_CHUNK + threadIdx.x * 4;
  int s = 0;
#pragma unroll
  for (int j = 0; j < 4; ++j) {
    int idx = c0 + j;
    if (idx < N) s += cnt[idx];
  }
  __shared__ int red[256];
  red[threadIdx.x] = s;
  __syncthreads();
  for (int o = 128; o > 0; o >>= 1) {
    if (threadIdx.x < o) red[threadIdx.x] += red[threadIdx.x + o];
    __syncthreads();
  }
  if (threadIdx.x == 0) chunkTot[blockIdx.x] = red[0];
}

__global__ __launch_bounds__(128) void k_scanB(const int* __restrict__ chunkTot,
                                               int* __restrict__ chunkOff, int nChunks) {
  __shared__ int buf[128];
  int t = threadIdx.x;
  int v = (t < nChunks) ? chunkTot[t] : 0;
  buf[t] = v;
  __syncthreads();
  for (int o = 1; o < 128; o <<= 1) {
    int x = buf[t];
    if (t >= o) x += buf[t - o];
    __syncthreads();
    buf[t] = x;
    __syncthreads();
  }
  if (t < nChunks) chunkOff[t] = buf[t] - v;   // exclusive
}

__global__ __launch_bounds__(256) void k_scanC(const int* __restrict__ cnt,
                                               const int* __restrict__ chunkOff,
                                               int* __restrict__ offs,
                                               float* __restrict__ dinv, int N) {
  int t = threadIdx.x;
  int c0 = blockIdx.x * SCAN_CHUNK + t * 4;
  int v[4];
  int s = 0;
#pragma unroll
  for (int j = 0; j < 4; ++j) {
    int idx = c0 + j;
    v[j] = (idx < N) ? cnt[idx] : 0;
    s += v[j];
  }
  __shared__ int buf[256];
  buf[t] = s;
  __syncthreads();
  for (int o = 1; o < 256; o <<= 1) {
    int x = buf[t];
    if (t >= o) x += buf[t - o];
    __syncthreads();
    buf[t] = x;
    __syncthreads();
  }
  int excl = buf[t] - s + chunkOff[blockIdx.x];
#pragma unroll
  for (int j = 0; j < 4; ++j) {
    int idx = c0 + j;
    if (idx < N) {
      offs[idx] = excl;
      dinv[idx] = rsqrtf((float)v[j] + 2.0f);   // deg + FILL(2.0) self-loop
      excl += v[j];
    }
  }
}

// ---------------------------------------------------------------------------
// Pass 2b: per-bucket CSR fill; cursors in LDS, contiguous csr range/block.
// ---------------------------------------------------------------------------
__global__ __launch_bounds__(256) void k_bfill(const int* __restrict__ gcur,
                                               const int* __restrict__ bdata,
                                               const int* __restrict__ offs,
                                               int* __restrict__ csr, int N) {
  __shared__ int lcur[1 << BUCK_SHIFT];
  const int b = blockIdx.x;
  const int tid = threadIdx.x;
  const int base = b << BUCK_SHIFT;
#pragma unroll
  for (int k = 0; k < (1 << BUCK_SHIFT); k += 256) {
    int node = base + k + tid;
    lcur[k + tid] = (node < N) ? offs[node] : 0;
  }
  __syncthreads();
  int nb = gcur[b];
  if (nb > BUCK_CAP) nb = BUCK_CAP;
  const int* bd = bdata + (size_t)b * BUCK_CAP;
  for (int i = tid; i < nb; i += 256) {
    int v = bd[i];
    int p = atomicAdd(&lcur[v >> 17], 1);
    csr[p] = v & 0x1FFFF;
  }
}

// ---------------------------------------------------------------------------
// One-time convert: W (3 layers) f32 -> fp16 TRANSPOSED [col][k].
// ---------------------------------------------------------------------------
__global__ __launch_bounds__(256) void k_wcvt(const float* __restrict__ W0,
                                              const float* __restrict__ Whid,
                                              _Float16* __restrict__ wt) {
  int g = blockIdx.x * 1024 + threadIdx.x * 4;
#pragma unroll
  for (int j = 0; j < 4; ++j) {
    int idx = g + j;                       // 0 .. 49151
    int layer = idx >> 14;
    int within = idx & 16383;              // = col*128 + k (dst order)
    int c = within >> 7, k = within & 127;
    const float* src = (layer == 0) ? W0 : Whid + (layer - 1) * 16384;
    wt[idx] = (_Float16)src[k * 128 + c];
  }
}

// ---------------------------------------------------------------------------
// MFMA GEMM: out[N,128] = dinv[row] * (H[N,128] @ W[128,128]), fp16 MFMA,
// f32 accumulate, fp16 out. PERSISTENT blocks: W staged in LDS once per
// block, then grid-stride over 64-row tiles (round-10: per-tile re-staging
// + barrier was ~half the kernel). F32IN: layer 0 reads f32 x directly,
// converting in-register (same rounding as the deleted k_xcvt pass).
// Fragment layouts: A row=l&15,k=(l>>4)*8+j; B col=l&15,k=(l>>4)*8+j;
// C col=l&15,row=(l>>4)*4+reg (m89-verified, dtype-independent).
// ---------------------------------------------------------------------------
template <bool F32IN>
__global__ __launch_bounds__(256) void k_gemm(const void* __restrict__ Hin,
                                              const _Float16* __restrict__ Wt,
                                              const float* __restrict__ dinv,
                                              _Float16* __restrict__ out, int nRows) {
  __shared__ _Float16 Wl[128][136];   // 34.8 KB

  const int tid = threadIdx.x;
  for (int i = tid; i < 128 * 16; i += 256) {
    int r = i >> 4, seg = i & 15;
    *reinterpret_cast<vhalf8*>(&Wl[r][seg * 8]) =
        *reinterpret_cast<const vhalf8*>(Wt + r * 128 + seg * 8);
  }
  __syncthreads();

  const int l = tid & 63;
  const int wv = tid >> 6;
  const int lrow = l & 15;
  const int lk8 = (l >> 4) * 8;
  const int nTiles = (nRows + 63) / 64;

#pragma unroll 1
  for (int tile = blockIdx.x; tile < nTiles; tile += gridDim.x) {
    const int rowBase = tile * 64 + wv * 16;

    vhalf8 a[4];
    int arow = rowBase + lrow;
    if (arow < nRows) {
      if constexpr (F32IN) {
        const float* ap = (const float*)Hin + (size_t)arow * 128 + lk8;
#pragma unroll
        for (int kc = 0; kc < 4; ++kc) {
          vfloat4 lo = *reinterpret_cast<const vfloat4*>(ap + kc * 32);
          vfloat4 hi = *reinterpret_cast<const vfloat4*>(ap + kc * 32 + 4);
          vhalf8 v;
          v[0] = (_Float16)lo.x; v[1] = (_Float16)lo.y;
          v[2] = (_Float16)lo.z; v[3] = (_Float16)lo.w;
          v[4] = (_Float16)hi.x; v[5] = (_Float16)hi.y;
          v[6] = (_Float16)hi.z; v[7] = (_Float16)hi.w;
          a[kc] = v;
        }
      } else {
        const _Float16* ap = (const _Float16*)Hin + (size_t)arow * 128 + lk8;
#pragma unroll
        for (int kc = 0; kc < 4; ++kc)
          a[kc] = *reinterpret_cast<const vhalf8*>(ap + kc * 32);
      }
    } else {
#pragma unroll
      for (int kc = 0; kc < 4; ++kc)
#pragma unroll
        for (int j = 0; j < 8; ++j) a[kc][j] = (_Float16)0.f;
    }

    f32x4 acc[8];
#pragma unroll
    for (int ct = 0; ct < 8; ++ct) acc[ct] = (f32x4)(0.f);

#pragma unroll
    for (int kc = 0; kc < 4; ++kc) {
#pragma unroll
      for (int ct = 0; ct < 8; ++ct) {
        vhalf8 b = *reinterpret_cast<const vhalf8*>(&Wl[ct * 16 + lrow][kc * 32 + lk8]);
        acc[ct] = __builtin_amdgcn_mfma_f32_16x16x32_f16(a[kc], b, acc[ct], 0, 0, 0);
      }
    }

    const int r0 = rowBase + (l >> 4) * 4;
    float dv[4];
#pragma unroll
    for (int r = 0; r < 4; ++r) dv[r] = (r0 + r < nRows) ? dinv[r0 + r] : 0.f;
#pragma unroll
    for (int ct = 0; ct < 8; ++ct) {
#pragma unroll
      for (int r = 0; r < 4; ++r) {
        int row = r0 + r;
        if (row < nRows)
          out[(size_t)row * 128 + ct * 16 + lrow] = (_Float16)(dv[r] * acc[ct][r]);
      }
    }
  }
}

// ---------------------------------------------------------------------------
// Aggregation: h[v] = tanh( dinv[v]*( sum_src tmp'[src] + 2*tmp'[v] ) + b )
// tmp' fp16 (dinv-pre-scaled); f32 accumulation; fp16 output.
// Half-wave per node, half4 per lane; edge loop x8, CSR int4 NT loads.
// ---------------------------------------------------------------------------
__device__ __forceinline__ float4 h2f(vhalf4 v) {
  return make_float4((float)v.x, (float)v.y, (float)v.z, (float)v.w);
}
__device__ __forceinline__ float4 add4(float4 a, float4 acc) {
  acc.x += a.x; acc.y += a.y; acc.z += a.z; acc.w += a.w;
  return acc;
}

__global__ __launch_bounds__(256) void k_agg(const _Float16* __restrict__ tmp,
                                             const int* __restrict__ offs,
                                             const int* __restrict__ cnt,
                                             const int* __restrict__ csr,
                                             const float* __restrict__ dinv,
                                             const float* __restrict__ bias,
                                             _Float16* __restrict__ hout, int N) {
  int node = (blockIdx.x * 256 + threadIdx.x) >> 5;
  if (node >= N) return;
  int lane = threadIdx.x & 31;

  float dv = dinv[node];

  const vhalf4* t4 = reinterpret_cast<const vhalf4*>(tmp);
  float4 hv = h2f(t4[(size_t)node * 32 + lane]);
  float4 acc = make_float4(2.f * hv.x, 2.f * hv.y, 2.f * hv.z, 2.f * hv.w);

  int s = offs[node], e = s + cnt[node];
  int i = s;

  for (; (i & 3) && i < e; ++i) {
    float4 a = h2f(t4[(size_t)csr[i] * 32 + lane]);
    acc = add4(a, acc);
  }

  const vint4* cp = reinterpret_cast<const vint4*>(csr);
  for (; i + 8 <= e; i += 8) {
    vint4 p0 = __builtin_nontemporal_load(&cp[(i >> 2) + 0]);
    vint4 p1 = __builtin_nontemporal_load(&cp[(i >> 2) + 1]);
    float4 a0 = h2f(t4[(size_t)p0.x * 32 + lane]);
    float4 a1 = h2f(t4[(size_t)p0.y * 32 + lane]);
    float4 a2 = h2f(t4[(size_t)p0.z * 32 + lane]);
    float4 a3 = h2f(t4[(size_t)p0.w * 32 + lane]);
    float4 a4 = h2f(t4[(size_t)p1.x * 32 + lane]);
    float4 a5 = h2f(t4[(size_t)p1.y * 32 + lane]);
    float4 a6 = h2f(t4[(size_t)p1.z * 32 + lane]);
    float4 a7 = h2f(t4[(size_t)p1.w * 32 + lane]);
    acc = add4(a0, acc); acc = add4(a1, acc);
    acc = add4(a2, acc); acc = add4(a3, acc);
    acc = add4(a4, acc); acc = add4(a5, acc);
    acc = add4(a6, acc); acc = add4(a7, acc);
  }
  for (; i + 4 <= e; i += 4) {
    vint4 p = __builtin_nontemporal_load(&cp[i >> 2]);
    float4 a0 = h2f(t4[(size_t)p.x * 32 + lane]);
    float4 a1 = h2f(t4[(size_t)p.y * 32 + lane]);
    float4 a2 = h2f(t4[(size_t)p.z * 32 + lane]);
    float4 a3 = h2f(t4[(size_t)p.w * 32 + lane]);
    acc = add4(a0, acc); acc = add4(a1, acc);
    acc = add4(a2, acc); acc = add4(a3, acc);
  }
  for (; i < e; ++i) {
    float4 a = h2f(t4[(size_t)csr[i] * 32 + lane]);
    acc = add4(a, acc);
  }

  float4 b4 = reinterpret_cast<const float4*>(bias)[lane];
  vhalf4 r;
  r.x = (_Float16)tanhf(fmaf(dv, acc.x, b4.x));
  r.y = (_Float16)tanhf(fmaf(dv, acc.y, b4.y));
  r.z = (_Float16)tanhf(fmaf(dv, acc.z, b4.z));
  r.w = (_Float16)tanhf(fmaf(dv, acc.w, b4.w));
  __builtin_nontemporal_store(r, &reinterpret_cast<vhalf4*>(hout)[(size_t)node * 32 + lane]);
}

// ---------------------------------------------------------------------------
// Pool (segment max + mean, h fp16) fused with the linear head.
// One block (512 threads = 4 row-stripes of 128 features) per graph.
// ---------------------------------------------------------------------------
__global__ __launch_bounds__(512) void k_pool(const _Float16* __restrict__ h,
                                              const int* __restrict__ batch,
                                              const float* __restrict__ Wout,
                                              const float* __restrict__ bout,
                                              float* __restrict__ out, int N) {
  int g = blockIdx.x;

  int lo = 0, hi = N;
  while (lo < hi) { int mid = (lo + hi) >> 1; if (batch[mid] < g) lo = mid + 1; else hi = mid; }
  int s = lo;
  int lo2 = s, hi2 = N;
  while (lo2 < hi2) { int mid = (lo2 + hi2) >> 1; if (batch[mid] < g + 1) lo2 = mid + 1; else hi2 = mid; }
  int e = lo2;

  int f = threadIdx.x & 127;
  int stripe = threadIdx.x >> 7;   // 0..3

  float mx = -INFINITY, sm = 0.f;
  for (int n = s + stripe; n < e; n += 4) {
    float v = (float)h[(size_t)n * NF + f];
    mx = fmaxf(mx, v);
    sm += v;
  }

  __shared__ float smx[4][NF];
  __shared__ float ssm[4][NF];
  smx[stripe][f] = mx;
  ssm[stripe][f] = sm;
  __syncthreads();

  if (stripe == 0) {
    mx = fmaxf(fmaxf(smx[0][f], smx[1][f]), fmaxf(smx[2][f], smx[3][f]));
    sm = ssm[0][f] + ssm[1][f] + ssm[2][f] + ssm[3][f];

    int cnt = e - s;
    float mean = sm / fmaxf((float)cnt, 1.0f);
    if (cnt == 0) mx = 0.f;

    float part = mx * Wout[f] + mean * Wout[NF + f];

    for (int o = 32; o > 0; o >>= 1) part += __shfl_down(part, o);
    __shared__ float wsum[2];
    if ((threadIdx.x & 63) == 0) wsum[threadIdx.x >> 6] = part;
    __syncthreads();
    if (threadIdx.x == 0) out[g] = wsum[0] + wsum[1] + bout[0];
  }
}

// ---------------------------------------------------------------------------
// Driver
// ---------------------------------------------------------------------------
extern "C" void kernel_launch(void* const* d_in, const int* in_sizes, int n_in,
                              void* d_out, int out_size, void* d_ws, size_t ws_size,
                              hipStream_t stream) {
  const float* x     = (const float*)d_in[0];
  const int*   eidx  = (const int*)d_in[1];     // [2][E]
  const int*   batch = (const int*)d_in[2];     // [N]
  const float* W0    = (const float*)d_in[3];
  const float* b0    = (const float*)d_in[4];
  const float* Whid  = (const float*)d_in[5];   // [2][128][128]
  const float* bhid  = (const float*)d_in[6];   // [2][128]
  const float* Wout  = (const float*)d_in[7];   // [256]
  const float* bout  = (const float*)d_in[8];   // [1]
  float* out = (float*)d_out;

  const int N = in_sizes[0] / NF;
  const int E = in_sizes[1] / 2;
  const int G = out_size;

  const int* erow = eidx;
  const int* ecol = eidx + E;

  // workspace layout (256B aligned)
  size_t off = 0;
  auto alloc = [&](size_t bytes) -> void* {
    void* p = (char*)d_ws + off;
    off += (bytes + 255) & ~(size_t)255;
    return p;
  };
  int*      gcur     = (int*)alloc(NBUCK_MAX * 4);
  int*      cnt      = (int*)alloc((size_t)N * 4);
  float*    dinv     = (float*)alloc((size_t)N * 4);
  int*      offs     = (int*)alloc((size_t)N * 4);
  int*      chunkTot = (int*)alloc(1024);
  int*      chunkOff = (int*)alloc(1024);
  int*      bdata    = (int*)alloc((size_t)NBUCK_MAX * BUCK_CAP * 4);  // 21 MB
  int*      csr      = (int*)alloc((size_t)E * 4);
  _Float16* wt       = (_Float16*)alloc(3 * 16384 * 2);                // 96 KB
  _Float16* tmp      = (_Float16*)alloc((size_t)N * NF * 2);
  _Float16* h        = (_Float16*)alloc((size_t)N * NF * 2);
  (void)ws_size;

  (void)hipMemsetAsync(gcur, 0, NBUCK_MAX * 4, stream);

  const int nChunks = (N + SCAN_CHUNK - 1) / SCAN_CHUNK;       // 98 for N=100k
  const int nbuck = (N + (1 << BUCK_SHIFT) - 1) >> BUCK_SHIFT; // 196 for N=100k

  k_bucket<<<512, 256, 0, stream>>>(erow, ecol, gcur, bdata, E);
  k_hist<<<nbuck, 256, 0, stream>>>(gcur, bdata, cnt, N);
  k_scanA<<<nChunks, 256, 0, stream>>>(cnt, chunkTot, N);
  k_scanB<<<1, 128, 0, stream>>>(chunkTot, chunkOff, nChunks);
  k_scanC<<<nChunks, 256, 0, stream>>>(cnt, chunkOff, offs, dinv, N);
  k_bfill<<<nbuck, 256, 0, stream>>>(gcur, bdata, offs, csr, N);
  k_wcvt<<<48, 256, 0, stream>>>(W0, Whid, wt);

  const int nTiles = (N + 63) / 64;
  const int gemmGrid = (nTiles < 784) ? nTiles : 784;   // persistent, ~2 tiles/block
  const int aggGrid = (N + 7) / 8;          // 8 nodes (half-waves) per 256-thr block

  // layer 0: x (f32, converted in-register) -> tmp -> h
  k_gemm<true><<<gemmGrid, 256, 0, stream>>>(x, wt, dinv, tmp, N);
  k_agg<<<aggGrid, 256, 0, stream>>>(tmp, offs, cnt, csr, dinv, b0, h, N);
  // layer 1
  k_gemm<false><<<gemmGrid, 256, 0, stream>>>(h, wt + 16384, dinv, tmp, N);
  k_agg<<<aggGrid, 256, 0, stream>>>(tmp, offs, cnt, csr, dinv, bhid, h, N);
  // layer 2
  k_gemm<false><<<gemmGrid, 256, 0, stream>>>(h, wt + 2 * 16384, dinv, tmp, N);
  k_agg<<<aggGrid, 256, 0, stream>>>(tmp, offs, cnt, csr, dinv, bhid + NF, h, N);

  // pooling + head
  k_pool<<<G, 512, 0, stream>>>(h, batch, Wout, bout, out, N);
}